// Round 10
// baseline (86.474 us; speedup 1.0000x reference)
//
#include <hip/hip_runtime.h>

#define NBINS 101
#define NB2 (2 * NBINS)    // 202 bins total (pos + neg)
#define NTHREADS 256
#define NCOPY 32           // histogram replicas, one per lane&31 (bank = copy)
#define CNT_SHIFT 22
#define QMAX 413695u       // (100<<12) | 4095 : clamps idx to <= 100
#define FSCALE 452.5483399593904f   // sqrt(50 * 4096): folds (s+1)*204800 into MFMA

typedef _Float16 half8 __attribute__((ext_vector_type(8)));
typedef float floatx4 __attribute__((ext_vector_type(4)));

// ---------------------------------------------------------------------------
// R10: dispatch-count reduction (3 -> 2). R9 accounting: fill 41.3us (fixed
// harness poison) + ~45us controllables, of which kernels model to only
// ~12-15us -> gaps/launch overhead dominate. Fuse the reduce into hist via
// the R3-proven last-block pattern (global fan-in with non-returning
// unsafeAtomicAdd = HBM-side RMW, device-coherent; counter handshake after
// __syncthreads vmcnt drain), and fold g_hist/count zeroing into the prep
// kernel (kernel boundary orders it before any hist atomic).
// ---------------------------------------------------------------------------

__global__ __launch_bounds__(NTHREADS)
void prep_kernel(const float* __restrict__ feats,
                 const int* __restrict__ classes,
                 _Float16* __restrict__ wsF,
                 unsigned char* __restrict__ wsC,
                 float* __restrict__ g_hist,      // [NB2] + counter behind it
                 unsigned* __restrict__ g_cnt,
                 int ngroups,   // N*D/8 groups of 8 floats
                 int n) {       // N (classes)
    int t = blockIdx.x * NTHREADS + threadIdx.x;
    if (t < ngroups) {
        const float4* p = (const float4*)feats + (size_t)t * 2;
        float4 f0 = p[0];
        float4 f1 = p[1];
        half8 h;
        h[0] = (_Float16)(f0.x * FSCALE); h[1] = (_Float16)(f0.y * FSCALE);
        h[2] = (_Float16)(f0.z * FSCALE); h[3] = (_Float16)(f0.w * FSCALE);
        h[4] = (_Float16)(f1.x * FSCALE); h[5] = (_Float16)(f1.y * FSCALE);
        h[6] = (_Float16)(f1.z * FSCALE); h[7] = (_Float16)(f1.w * FSCALE);
        *(half8*)(wsF + (size_t)t * 8) = h;
    }
    if (t < n) wsC[t] = (unsigned char)classes[t];
    if (blockIdx.x == 0) {
        if (threadIdx.x < NB2) g_hist[threadIdx.x] = 0.0f;
        if (threadIdx.x == NTHREADS - 1) *g_cnt = 0u;
    }
}

// ---------------------------------------------------------------------------
// One 64x64 upper-triangular tile per wave; half8 fragment loads from the
// scaled f16 workspace; acc arrives in q-space (bias pre-added); one
// ds_add_u32 per pair; per-block unpack + telescope -> 202 global fan-in
// atomics; last block finalizes inline.
// ---------------------------------------------------------------------------
__global__ __launch_bounds__(NTHREADS, 4)
void hist_pairs_kernel(const _Float16* __restrict__ feats16,
                       const unsigned char* __restrict__ cls8,
                       float* __restrict__ g_hist,
                       unsigned* __restrict__ g_cnt,
                       float* __restrict__ out,
                       int ntiles, int njobs) {
    __shared__ unsigned lhist[NB2][NCOPY];   // packed count|frac, 25.9 KB
    __shared__ float Fbuf[NB2];
    __shared__ float hfin[NB2];
    __shared__ __align__(16) int cls[4][2][64];  // [wave][A/B][row]
    __shared__ bool s_last;

    const int tid = threadIdx.x;
    const int wave = tid >> 6;
    const int lane = tid & 63;

    // zero local histograms (uint4 stores)
    {
        uint4* z = (uint4*)&lhist[0][0];
        uint4 zero = {0u, 0u, 0u, 0u};
        for (int t = tid; t < NB2 * NCOPY / 4; t += NTHREADS) z[t] = zero;
    }

    // one 64x64 upper-triangular tile per wave
    const int job = blockIdx.x * 4 + wave;
    int ti = 0, tj = 0;
    if (job < njobs) {
        int rem = job;
        while (rem >= ntiles - ti) { rem -= ntiles - ti; ++ti; }
        tj = ti + rem;
        cls[wave][0][lane] = cls8[ti * 64 + lane];
        cls[wave][1][lane] = cls8[tj * 64 + lane];
    }
    __syncthreads();

    if (job < njobs) {
        const int i0 = ti * 64, j0 = tj * 64;
        const int lr = lane & 15;
        const int quad = lane >> 4;

        const _Float16* Ab = feats16 + (size_t)(i0 + lr) * 128 + quad * 8;
        const _Float16* Bb = feats16 + (size_t)(j0 + lr) * 128 + quad * 8;

        // acc initialized to the binning bias: (s+1)*204800 + 0.5 rounding
        floatx4 acc[4][4];
        #pragma unroll
        for (int mi = 0; mi < 4; ++mi)
            #pragma unroll
            for (int ni = 0; ni < 4; ++ni) {
                acc[mi][ni][0] = 204800.5f; acc[mi][ni][1] = 204800.5f;
                acc[mi][ni][2] = 204800.5f; acc[mi][ni][3] = 204800.5f;
            }

        #pragma unroll
        for (int ks = 0; ks < 128; ks += 32) {
            half8 af[4], bf[4];
            #pragma unroll
            for (int mi = 0; mi < 4; ++mi)
                af[mi] = *(const half8*)(Ab + (size_t)mi * 16 * 128 + ks);
            #pragma unroll
            for (int ni = 0; ni < 4; ++ni)
                bf[ni] = *(const half8*)(Bb + (size_t)ni * 16 * 128 + ks);
            #pragma unroll
            for (int mi = 0; mi < 4; ++mi)
                #pragma unroll
                for (int ni = 0; ni < 4; ++ni)
                    acc[mi][ni] = __builtin_amdgcn_mfma_f32_16x16x32_f16(
                        af[mi], bf[ni], acc[mi][ni], 0, 0, 0);
        }

        // classes for this lane's C fragment rows/cols
        int cA[4][4], cB[4];
        #pragma unroll
        for (int mi = 0; mi < 4; ++mi) {
            int4 c4 = *(const int4*)&cls[wave][0][mi * 16 + quad * 4];
            cA[mi][0] = c4.x; cA[mi][1] = c4.y;
            cA[mi][2] = c4.z; cA[mi][3] = c4.w;
        }
        #pragma unroll
        for (int ni = 0; ni < 4; ++ni) cB[ni] = cls[wave][1][ni * 16 + lr];

        // binning: acc already equals q + tiny fp noise. One ds_add_u32/pair.
        const int copy = lane & (NCOPY - 1);
        unsigned* hb = &lhist[0][0] + copy;
        const bool diag = (ti == tj);
        #pragma unroll
        for (int mi = 0; mi < 4; ++mi) {
            #pragma unroll
            for (int ni = 0; ni < 4; ++ni) {
                #pragma unroll
                for (int r = 0; r < 4; ++r) {
                    const int li = mi * 16 + quad * 4 + r;
                    const int lj = ni * 16 + lr;
                    if (diag && li >= lj) continue;  // strict upper triangle
                    float qf = fmaxf(acc[mi][ni][r], 0.0f);
                    unsigned q = (unsigned)qf;
                    q = q > QMAX ? QMAX : q;
                    unsigned idx = q >> 12;
                    unsigned word = (q & 4095u) | (1u << CNT_SHIFT);
                    unsigned hoff = (cA[mi][r] == cB[ni]) ? 0u : (unsigned)NBINS;
                    atomicAdd(hb + (hoff + idx) * NCOPY, word);
                }
            }
        }
    }
    __syncthreads();

    // per-bin unpack: C = sum(w>>22), F = sum(w&mask)/4096, then telescope:
    // h[t] = C[t] - (t<hi)F[t] + (t>lo)F[t-1]  per 101-bin segment
    const int t = tid;
    float myC = 0.0f, myF = 0.0f;
    if (t < NB2) {
        unsigned Cs = 0, Fq = 0;
        #pragma unroll
        for (int c = 0; c < NCOPY; ++c) {
            unsigned w = lhist[t][(c + t) & (NCOPY - 1)];
            Cs += w >> CNT_SHIFT;
            Fq += w & ((1u << CNT_SHIFT) - 1);   // <= 32*2^21 = 2^26, safe
        }
        myC = (float)Cs;
        myF = (float)Fq * (1.0f / 4096.0f);
        Fbuf[t] = myF;
    }
    __syncthreads();
    if (t < NB2) {
        const int lo = (t < NBINS) ? 0 : NBINS;
        const int hi = lo + NBINS - 1;
        float h = myC;
        if (t < hi) h -= myF;
        if (t > lo) h += Fbuf[t - 1];
        unsafeAtomicAdd(&g_hist[t], h);   // non-returning HBM-side RMW
    }
    __syncthreads();   // drains each wave's vmcnt before the handshake

    if (tid == 0) {
        __threadfence();
        unsigned old = atomicAdd(g_cnt, 1u);
        s_last = (old == gridDim.x - 1);
    }
    __syncthreads();
    if (!s_last) return;

    __threadfence();
    if (tid < NB2)
        hfin[tid] = __hip_atomic_load(&g_hist[tid], __ATOMIC_RELAXED,
                                      __HIP_MEMORY_SCOPE_AGENT);
    __syncthreads();
    if (tid == 0) {
        double sp = 0.0, sn = 0.0;
        for (int k = 0; k < NBINS; ++k) { sp += hfin[k]; sn += hfin[NBINS + k]; }
        double isp = 1.0 / sp, isn = 1.0 / sn;
        double cdf = 0.0, res = 0.0;
        for (int k = 0; k < NBINS; ++k) {
            cdf += (double)hfin[k] * isp;                 // cumsum of pos
            res += (double)hfin[NBINS + k] * isn * cdf;   // dot with neg
        }
        out[0] = (float)res;
    }
}

extern "C" void kernel_launch(void* const* d_in, const int* in_sizes, int n_in,
                              void* d_out, int out_size, void* d_ws, size_t ws_size,
                              hipStream_t stream) {
    const float* feats   = (const float*)d_in[0];
    const int*   classes = (const int*)d_in[1];
    float* out = (float*)d_out;

    int N = in_sizes[1];                       // 4096
    int D = in_sizes[0] / N;                   // 128
    int ntiles = N / 64;                       // 64
    int njobs = ntiles * (ntiles + 1) / 2;     // 2080 wave-jobs
    int nblocks = (njobs + 3) / 4;             // 520 blocks, 4 jobs each

    // workspace layout: f16 scaled feats | g_hist[202] | counter | u8 classes
    _Float16* wsF = (_Float16*)d_ws;
    float* g_hist = (float*)(wsF + (size_t)N * D);
    unsigned* g_cnt = (unsigned*)(g_hist + NB2);
    unsigned char* wsC = (unsigned char*)(g_cnt + 2);

    int ngroups = N * D / 8;                   // 65536 groups of 8 floats
    int cblocks = (ngroups + NTHREADS - 1) / NTHREADS;
    prep_kernel<<<cblocks, NTHREADS, 0, stream>>>(feats, classes, wsF, wsC,
                                                  g_hist, g_cnt, ngroups, N);
    hist_pairs_kernel<<<nblocks, NTHREADS, 0, stream>>>(wsF, wsC, g_hist, g_cnt,
                                                        out, ntiles, njobs);
}